// Round 5
// baseline (568.921 us; speedup 1.0000x reference)
//
#include <hip/hip_runtime.h>
#include <hip/hip_bf16.h>
#include <stdint.h>

#define B_ 256
#define T_ 512
#define V_ 30000
#define E_ 256
#define H_ 32

typedef float v2f __attribute__((ext_vector_type(2)));

// ---------------------------------------------------------------------------
// Fast activations (fp32, saturate cleanly at extremes: no NaN)
// ---------------------------------------------------------------------------
__device__ __forceinline__ float sigmoidf_fast(float x) {
    return 1.0f / (1.0f + __expf(-x));
}
__device__ __forceinline__ float tanhf_fast(float x) {
    return 1.0f - 2.0f / (1.0f + __expf(2.0f * x));
}
__device__ __forceinline__ uint32_t rlu(float v, int lane) {
    return (uint32_t)__builtin_amdgcn_readlane(__float_as_int(v), lane);
}
// packed fp32 FMA: acc.{lo,hi} += w.{lo,hi} * h{k,k+1}  (h-pair in SGPR pair)
__device__ __forceinline__ void pk_fma(v2f& acc, v2f w, uint64_t hh) {
    asm("v_pk_fma_f32 %0, %1, %2, %0" : "+v"(acc) : "v"(w), "s"(hh));
}

// ---------------------------------------------------------------------------
// GEMM: Out[M,192] = A[M,K] @ Wcat[192,K]^T + bias   (unchanged)
// ---------------------------------------------------------------------------
#define GEMM_MT 64
#define GEMM_KC 32
#define GEMM_PA 68
#define GEMM_PB 196

__global__ __launch_bounds__(256) void gemm_gates(
    const float* __restrict__ A, int M, int K,
    const float* __restrict__ Wf, const float* __restrict__ Wb,
    const float* __restrict__ bihf, const float* __restrict__ bhhf,
    const float* __restrict__ bihb, const float* __restrict__ bhhb,
    float* __restrict__ Out)
{
    __shared__ float As[GEMM_KC][GEMM_PA];
    __shared__ float Bs[GEMM_KC][GEMM_PB];

    const int tid = threadIdx.x;
    const int mbase = blockIdx.x * GEMM_MT;
    const int mg = tid >> 5, ng = tid & 31;
    const int m_off = mg * 8, n_off = ng * 6;

    float acc[8][6];
    #pragma unroll
    for (int r = 0; r < 8; ++r)
        #pragma unroll
        for (int c = 0; c < 6; ++c) acc[r][c] = 0.f;

    for (int kc = 0; kc < K; kc += GEMM_KC) {
        #pragma unroll
        for (int i = 0; i < 2; ++i) {
            int fi = tid + 256 * i;
            int row = fi >> 3, cf = fi & 7;
            int m = mbase + row;
            float4 v = make_float4(0.f, 0.f, 0.f, 0.f);
            if (m < M) v = *(const float4*)&A[(size_t)m * K + kc + cf * 4];
            As[cf * 4 + 0][row] = v.x; As[cf * 4 + 1][row] = v.y;
            As[cf * 4 + 2][row] = v.z; As[cf * 4 + 3][row] = v.w;
        }
        #pragma unroll
        for (int i = 0; i < 6; ++i) {
            int fi = tid + 256 * i;
            int g = fi >> 3, cf = fi & 7;
            const float* Wsel = (g < 96) ? (Wf + (size_t)g * K)
                                         : (Wb + (size_t)(g - 96) * K);
            float4 v = *(const float4*)&Wsel[kc + cf * 4];
            Bs[cf * 4 + 0][g] = v.x; Bs[cf * 4 + 1][g] = v.y;
            Bs[cf * 4 + 2][g] = v.z; Bs[cf * 4 + 3][g] = v.w;
        }
        __syncthreads();
        #pragma unroll
        for (int k = 0; k < GEMM_KC; ++k) {
            float a[8], bb[6];
            *(float4*)&a[0] = *(const float4*)&As[k][m_off];
            *(float4*)&a[4] = *(const float4*)&As[k][m_off + 4];
            *(float2*)&bb[0] = *(const float2*)&Bs[k][n_off];
            *(float2*)&bb[2] = *(const float2*)&Bs[k][n_off + 2];
            *(float2*)&bb[4] = *(const float2*)&Bs[k][n_off + 4];
            #pragma unroll
            for (int r = 0; r < 8; ++r)
                #pragma unroll
                for (int c = 0; c < 6; ++c)
                    acc[r][c] = fmaf(a[r], bb[c], acc[r][c]);
        }
        __syncthreads();
    }

    float bias[6];
    #pragma unroll
    for (int c = 0; c < 6; ++c) {
        int g = n_off + c;
        int g96 = (g < 96) ? g : g - 96;
        const float* bih = (g < 96) ? bihf : bihb;
        const float* bhh = (g < 96) ? bhhf : bhhb;
        bias[c] = bih[g96] + ((g96 < 64) ? bhh[g96] : 0.f);
    }
    #pragma unroll
    for (int r = 0; r < 8; ++r) {
        int m = mbase + m_off + r;
        if (m < M) {
            float* op = &Out[(size_t)m * 192 + n_off];
            #pragma unroll
            for (int c = 0; c < 6; ++c) op[c] = acc[r][c] + bias[c];
        }
    }
}

// ---------------------------------------------------------------------------
// GRU scan. One wave per (batch, direction). h[j] in lane j (j<32); every
// lane computes ALL THREE gates for its unit (upper half redundant).
// Recurrent matvec: 48 v_pk_fma_f32 with h broadcast via readlane->SGPR pair.
// amdgpu_waves_per_eu(1,1): grid caps occupancy at <=1 wave/SIMD anyway;
// pinning it lets the allocator use the full 256-VGPR budget so wR/wZ/wN
// stay in arch VGPRs (at 64 VGPRs they spill to AGPRs and every pk_fma's
// "v"-constrained asm operand forces v_accvgpr_read copies = ~96 extra
// VALU/step — the R4 issue bloat).
// gi prefetch: 128 chunks of 4 steps, two register banks alternate per chunk
// (4-body distance, no copy ever reads an in-flight load).
// ---------------------------------------------------------------------------
template <int USE_IDS>
__global__ __launch_bounds__(64)
__attribute__((amdgpu_waves_per_eu(1, 1)))
void gru_scan(
    const float* __restrict__ gi,     // [rows,192]: G0 (gather) or gi1 (direct)
    const int* __restrict__ ids,
    const int* __restrict__ mask,
    const float* __restrict__ Whh_f, const float* __restrict__ Whh_b,
    const float* __restrict__ bhh_f, const float* __restrict__ bhh_b,
    float* __restrict__ out_seq,      // [B,T,64] or nullptr
    float* __restrict__ out_fin)      // [B,64]   or nullptr
{
    const int l = threadIdx.x;
    const int j = l & 31;
    const bool lower = l < 32;
    const int dir = blockIdx.x & 1;
    const int b = blockIdx.x >> 1;
    const int bT = b * T_;

    const float* Whh = dir ? Whh_b : Whh_f;
    const float* bhh = dir ? bhh_b : bhh_f;

    // per-lane weight rows (r=j, z=32+j, n=64+j) as fp32 pairs
    v2f wR[16], wZ[16], wN[16];
    #pragma unroll
    for (int q = 0; q < 16; ++q) {
        wR[q] = *(const v2f*)&Whh[j * 32 + 2 * q];
        wZ[q] = *(const v2f*)&Whh[(32 + j) * 32 + 2 * q];
        wN[q] = *(const v2f*)&Whh[(64 + j) * 32 + 2 * q];
    }
    const float bn = bhh[64 + j];

    const int offR = dir * 96 + j;
    const int offZ = dir * 96 + 32 + j;
    const int offN = dir * 96 + 64 + j;

    // int4 word base for chunk c (fwd: t=4c..4c+3; bwd: t=511-4c..508-4c)
    auto wbase = [&](int c) { return dir ? (bT + 508 - 4 * c) : (bT + 4 * c); };

    // ---- prologue ----
    int4 ids0 = make_int4(0, 0, 0, 0);
    if (USE_IDS) ids0 = *(const int4*)&ids[wbase(0)];
    int4 mask_use = *(const int4*)&mask[wbase(0)];
    int4 mask_mid = *(const int4*)&mask[wbase(1)];
    int4 mask_in  = make_int4(0, 0, 0, 0);
    int4 ids_pf = make_int4(0, 0, 0, 0), ids_mid = ids_pf, ids_in = ids_pf;
    if (USE_IDS) {
        ids_pf  = *(const int4*)&ids[wbase(1)];
        ids_mid = *(const int4*)&ids[wbase(2)];
    }

    float gR[2][4], gZ[2][4], gN[2][4];
    #pragma unroll
    for (int u = 0; u < 4; ++u) {
        int row;
        if (USE_IDS) {
            const int* ip = (const int*)&ids0;
            row = dir ? ip[3 - u] : ip[u];
        } else {
            row = bT + (dir ? (511 - u) : u);
        }
        const float* gp = gi + (size_t)row * 192;
        gR[0][u] = gp[offR];
        gZ[0][u] = gp[offZ];
        gN[0][u] = gp[offN];
    }

    float h = 0.f;

    for (int c2 = 0; c2 < 64; ++c2) {
        #pragma unroll
        for (int p = 0; p < 2; ++p) {
            const int c = 2 * c2 + p;
            // far prefetch: ids for chunk c+3, mask for chunk c+2 (clamped)
            if (USE_IDS) {
                const int ci = (c + 3 < 128) ? (c + 3) : 127;
                ids_in = *(const int4*)&ids[wbase(ci)];
            }
            {
                const int cm = (c + 2 < 128) ? (c + 2) : 127;
                mask_in = *(const int4*)&mask[wbase(cm)];
            }
            const int cN = (c + 1 < 128) ? (c + 1) : 127;  // gi prefetch chunk

            #pragma unroll
            for (int u = 0; u < 4; ++u) {
                // --- issue gi prefetch for chunk c+1, body u, into bank p^1
                int rowN;
                if (USE_IDS) {
                    const int* ip = (const int*)&ids_pf;
                    rowN = dir ? ip[3 - u] : ip[u];
                } else {
                    rowN = bT + (dir ? (511 - 4 * cN - u) : (4 * cN + u));
                }
                const float* gpN = gi + (size_t)rowN * 192;
                gR[p ^ 1][u] = gpN[offR];
                gZ[p ^ 1][u] = gpN[offZ];
                gN[p ^ 1][u] = gpN[offN];

                // --- compute step (uses bank p, loaded during chunk c-1)
                const int* mu = (const int*)&mask_use;
                const int m = dir ? mu[3 - u] : mu[u];

                v2f aR = {0.f, 0.f}, aZ = {0.f, 0.f}, aN = {0.f, 0.f};
                #pragma unroll
                for (int k = 0; k < 16; ++k) {
                    const uint32_t hlo = rlu(h, 2 * k);
                    const uint32_t hhi = rlu(h, 2 * k + 1);
                    const uint64_t hh = ((uint64_t)hhi << 32) | hlo;
                    pk_fma(aR, wR[k], hh);
                    pk_fma(aZ, wZ[k], hh);
                    pk_fma(aN, wN[k], hh);
                }
                const float r  = sigmoidf_fast(gR[p][u] + aR.x + aR.y);
                const float z  = sigmoidf_fast(gZ[p][u] + aZ.x + aZ.y);
                const float hn = bn + aN.x + aN.y;
                const float n  = tanhf_fast(gN[p][u] + r * hn);
                const float hnew = n + z * (h - n);      // (1-z)n + z h
                h = m ? hnew : h;                        // packed-seq freeze

                if (out_seq != nullptr) {
                    const int t = dir ? (511 - 4 * c - u) : (4 * c + u);
                    if (lower)
                        out_seq[(size_t)(bT + t) * 64 + dir * 32 + j] = h;
                }
            }
            // --- rotate chunk-granular prefetch regs (1-chunk distance)
            mask_use = mask_mid; mask_mid = mask_in;
            if (USE_IDS) { ids_pf = ids_mid; ids_mid = ids_in; }
        }
    }

    if (out_fin != nullptr && lower)
        out_fin[b * 64 + dir * 32 + j] = h;
}

// ---------------------------------------------------------------------------
// Head: out[b,o] = hfin[b,:] . Wout[o,:] + bout[o]
// ---------------------------------------------------------------------------
__global__ void head_kernel(const float* __restrict__ hfin,
                            const float* __restrict__ Wout,
                            const float* __restrict__ bout,
                            float* __restrict__ out)
{
    int idx = blockIdx.x * blockDim.x + threadIdx.x;
    if (idx >= B_ * 6) return;
    int b = idx / 6, o = idx % 6;
    float acc = bout[o];
    const float* hp = hfin + b * 64;
    const float* wp = Wout + o * 64;
    #pragma unroll
    for (int k = 0; k < 64; ++k) acc = fmaf(hp[k], wp[k], acc);
    out[idx] = acc;
}

// ---------------------------------------------------------------------------
extern "C" void kernel_launch(void* const* d_in, const int* in_sizes, int n_in,
                              void* d_out, int out_size, void* d_ws, size_t ws_size,
                              hipStream_t stream)
{
    const int*   ids   = (const int*)d_in[0];
    const int*   mask  = (const int*)d_in[1];
    const float* embed = (const float*)d_in[2];
    const float* Wih0f = (const float*)d_in[3];
    const float* Whh0f = (const float*)d_in[4];
    const float* bih0f = (const float*)d_in[5];
    const float* bhh0f = (const float*)d_in[6];
    const float* Wih0b = (const float*)d_in[7];
    const float* Whh0b = (const float*)d_in[8];
    const float* bih0b = (const float*)d_in[9];
    const float* bhh0b = (const float*)d_in[10];
    const float* Wih1f = (const float*)d_in[11];
    const float* Whh1f = (const float*)d_in[12];
    const float* bih1f = (const float*)d_in[13];
    const float* bhh1f = (const float*)d_in[14];
    const float* Wih1b = (const float*)d_in[15];
    const float* Whh1b = (const float*)d_in[16];
    const float* bih1b = (const float*)d_in[17];
    const float* bhh1b = (const float*)d_in[18];
    const float* Wout  = (const float*)d_in[19];
    const float* bout  = (const float*)d_in[20];

    // workspace layout (floats):
    //   gbuf : G0 [V,192] (K1,K2) then gi1 [B*T,192] (K3,K4)
    //   x1   : [B,T,64]
    //   hfin : [B,64]
    float* ws   = (float*)d_ws;
    float* gbuf = ws;
    float* x1   = ws + (size_t)B_ * T_ * 192;
    float* hfin = x1 + (size_t)B_ * T_ * 64;

    // K1: vocab-factored layer-0 input gates  G0 = embed @ Wcat0^T + bias
    gemm_gates<<<(V_ + GEMM_MT - 1) / GEMM_MT, 256, 0, stream>>>(
        embed, V_, E_, Wih0f, Wih0b, bih0f, bhh0f, bih0b, bhh0b, gbuf);

    // K2: layer-0 bidirectional scan (gathers G0[id]), writes x1
    gru_scan<1><<<2 * B_, 64, 0, stream>>>(
        gbuf, ids, mask, Whh0f, Whh0b, bhh0f, bhh0b, x1, nullptr);

    // K3: layer-1 input gates  gi1 = x1 @ Wcat1^T + bias  (overwrites dead G0)
    gemm_gates<<<(B_ * T_) / GEMM_MT, 256, 0, stream>>>(
        x1, B_ * T_, 64, Wih1f, Wih1b, bih1f, bhh1f, bih1b, bhh1b, gbuf);

    // K4: layer-1 scan, final hiddens only
    gru_scan<0><<<2 * B_, 64, 0, stream>>>(
        gbuf, nullptr, mask, Whh1f, Whh1b, bhh1f, bhh1b, nullptr, hfin);

    // K5: output head
    head_kernel<<<(B_ * 6 + 255) / 256, 256, 0, stream>>>(hfin, Wout, bout,
                                                          (float*)d_out);
}